// Round 18
// baseline (93.568 us; speedup 1.0000x reference)
//
#include <hip/hip_runtime.h>

#define HH 512
#define IND 13
#define NN 2048
#define RR 256
#define WDIM 7168      // (13+1)*512
#define W1DIM 6656     // 13*512
#define NBLK 512       // n per block (4 waves x 128 n, nt=8)
#define NTHREADS 256
#define NEG_HALF_LOG_2PI (-0.91893853320467274f)

typedef __attribute__((ext_vector_type(8))) short short8;   // 8 bf16 (4 VGPRs) MFMA A/B frag
typedef __attribute__((ext_vector_type(4))) float f32x4;    // MFMA C/D frag
typedef __attribute__((ext_vector_type(2))) float f32x2;    // packed-math pair

// fp32 -> bf16 round-to-nearest-even (bit pattern) -- used for w1 (error-dominant term)
__device__ __forceinline__ short f2bf(float f) {
    unsigned u = __float_as_uint(f);
    u += 0x7fffu + ((u >> 16) & 1u);
    return (short)(u >> 16);
}

// R18 = green R17 restructured for per-MFMA overhead amortization:
//   nt 4 -> 8 (wave covers 128 n): a-frag read, w2 read, and t-loop addressing
//   serve 8 MFMAs instead of 4; bfrag-build work per n halves. NBLK=512 with
//   NO halves (same staging amortization as R17's 2-half scheme), grid (256,4).
//   czero hoisted loop-invariant (exonerated: R3-R5 reds all trace to the
//   divergent-partial-short8-write bug; greens R14+ are branch-free).
// Evidence basis (R16 counters): ~4200 VALU issues/wave vs ~1400 in source --
// per-MFMA hidden overhead (AGPR init/moves, scalarized max since VOP3P has
// pk_fma_f32 but NO pk_max_f32) dominates; R16(8w/SIMD,43us) vs R17(4w,~39.6us)
// shows issue-bound not latency-bound => fewer, fatter waves win.
// Ledger: relu-split BANNED (R3/R4/R15); divergent partial short8 writes
// BANNED (R11/R12); 256 thr, lb(,3), branch-free builds, direct relu = green.
// Structure: single-copy 16-short w1 rows, q-parity A reads, truncation hi/lo
// x split across q-halves, LDS 18432 B, grid (256,4) r-fast (XCD locality).
__global__ __launch_bounds__(NTHREADS, 3)
void ffrelu_mfma_kernel(const float* __restrict__ x,
                        const float* __restrict__ y,
                        const float* __restrict__ w,
                        float* __restrict__ out) {
    __shared__ short Als[HH * 16];   // 16384 B: w1 rows [w1(13)|0(3)]
    __shared__ float w2s[HH];        // 2048 B, fp32

    const int tid = threadIdx.x;
    const int r = blockIdx.x;       // fast dim: same-r blocks -> same XCD
    const int wave = tid >> 6;
    const int lane = tid & 63;
    const int m = lane & 15;        // MFMA row/col index within 16
    const int q = lane >> 4;        // quad 0..3

    const float* wr = w + (size_t)r * WDIM;

    // ---- stage w1 (bf16 RNE, 2 rows/thread, pads inline) + w2; ONE barrier ----
#pragma unroll
    for (int rr = 0; rr < 2; ++rr) {
        const int h = tid * 2 + rr;
        const float* p = wr + (size_t)h * IND;
        short tmp[16];
#pragma unroll
        for (int i = 0; i < 13; ++i) tmp[i] = f2bf(p[i]);
        tmp[13] = 0; tmp[14] = 0; tmp[15] = 0;
        *(short8*)&Als[h * 16]     = *(short8*)&tmp[0];
        *(short8*)&Als[h * 16 + 8] = *(short8*)&tmp[8];
    }
    w2s[tid]       = wr[W1DIM + tid];
    w2s[tid + 256] = wr[W1DIM + tid + 256];
    __syncthreads();

    const bool lo  = (q >= 2);     // q2/q3 lanes carry x_lo
    const bool hi8 = (q & 1);      // q1/q3 lanes carry slice [8..12]
    const f32x2 zero2 = {0.0f, 0.0f};
    const f32x4 czero = {0.0f, 0.0f, 0.0f, 0.0f};   // loop-invariant C operand

    // ---- build 8 B-frags (128 n per wave): branch-free truncation hi/lo split ----
    const int nb = blockIdx.y * NBLK + wave * 128;
    short8 bfrag[8];
#pragma unroll
    for (int nt = 0; nt < 8; ++nt) {
        const float* xp = x + (size_t)(nb + nt * 16 + m) * IND;
        short hs[13], ls[13];
#pragma unroll
        for (int i = 0; i < 13; ++i) {
            float v = xp[i];
            unsigned u = __float_as_uint(v);
            hs[i] = (short)(u >> 16);                         // truncate to bf16
            float res = v - __uint_as_float(u & 0xffff0000u); // exact remainder
            ls[i] = (short)(__float_as_uint(res) >> 16);      // truncate remainder
        }
        short s[13];
#pragma unroll
        for (int i = 0; i < 13; ++i) s[i] = lo ? ls[i] : hs[i];
        short8 b;
        b[0] = hi8 ? s[8]     : s[0];
        b[1] = hi8 ? s[9]     : s[1];
        b[2] = hi8 ? s[10]    : s[2];
        b[3] = hi8 ? s[11]    : s[3];
        b[4] = hi8 ? s[12]    : s[4];
        b[5] = hi8 ? (short)0 : s[5];
        b[6] = hi8 ? (short)0 : s[6];
        b[7] = hi8 ? (short)0 : s[7];
        bfrag[nt] = b;
    }

    // packed accumulators: muv[nt][0] covers regs {0,1}, muv[nt][1] regs {2,3}
    f32x2 muv[8][2];
#pragma unroll
    for (int i = 0; i < 8; ++i) {
        muv[i][0] = zero2;
        muv[i][1] = zero2;
    }

    // ---- main loop: 32 h-tiles x 8 n-tiles; packed relu+dot ----
#pragma unroll 2
    for (int t = 0; t < 32; ++t) {
        const short8 a = *(const short8*)&Als[(t * 16 + m) * 16 + (q & 1) * 8];
        const f32x4 wv = *(const f32x4*)&w2s[t * 16 + q * 4];
        const f32x2 wv01 = {wv[0], wv[1]};
        const f32x2 wv23 = {wv[2], wv[3]};
#pragma unroll
        for (int nt = 0; nt < 8; ++nt) {
            f32x4 c = __builtin_amdgcn_mfma_f32_16x16x32_bf16(a, bfrag[nt], czero, 0, 0, 0);
            // C layout: col n = lane&15, row h = t*16 + q*4 + reg
            f32x2 c01 = {c[0], c[1]};
            f32x2 c23 = {c[2], c[3]};
            c01 = __builtin_elementwise_max(c01, zero2);
            c23 = __builtin_elementwise_max(c23, zero2);
            muv[nt][0] += c01 * wv01;    // v_pk_fma_f32
            muv[nt][1] += c23 * wv23;
        }
    }

    // ---- horizontal sum + quad butterfly ----
    float mu[8];
#pragma unroll
    for (int nt = 0; nt < 8; ++nt) {
        f32x2 p = muv[nt][0] + muv[nt][1];
        float v = p[0] + p[1];
        v += __shfl_xor(v, 16, 64);
        v += __shfl_xor(v, 32, 64);
        mu[nt] = v;
    }

    // lane stores n = nb + s*64 + lane (s=0,1) -> tiles nt = q and 4+q
    float mu0, mu1;
    if (q == 0)      { mu0 = mu[0]; mu1 = mu[4]; }
    else if (q == 1) { mu0 = mu[1]; mu1 = mu[5]; }
    else if (q == 2) { mu0 = mu[2]; mu1 = mu[6]; }
    else             { mu0 = mu[3]; mu1 = mu[7]; }

    {
        const int n0 = nb + lane;
        float resid = y[n0] - mu0;
        out[(size_t)r * NN + n0] = fmaf(-0.5f * resid, resid, NEG_HALF_LOG_2PI);
    }
    {
        const int n1 = nb + 64 + lane;
        float resid = y[n1] - mu1;
        out[(size_t)r * NN + n1] = fmaf(-0.5f * resid, resid, NEG_HALF_LOG_2PI);
    }
}

extern "C" void kernel_launch(void* const* d_in, const int* in_sizes, int n_in,
                              void* d_out, int out_size, void* d_ws, size_t ws_size,
                              hipStream_t stream) {
    const float* x = (const float*)d_in[0];   // [N, 13]
    const float* y = (const float*)d_in[1];   // [N, 1]
    const float* w = (const float*)d_in[2];   // [R, 7168]
    float* out = (float*)d_out;               // [R, N]

    dim3 grid(RR, NN / NBLK);   // (256, 4): r fast -> same-r blocks share an XCD
    dim3 block(NTHREADS);
    ffrelu_mfma_kernel<<<grid, block, 0, stream>>>(x, y, w, out);
}

// Round 19
// 93.350 us; speedup vs baseline: 1.0023x; 1.0023x over previous
//
#include <hip/hip_runtime.h>

#define HH 512
#define IND 13
#define NN 2048
#define RR 256
#define WDIM 7168      // (13+1)*512
#define W1DIM 6656     // 13*512
#define NBLK 512       // n per block (4 waves x 128 n, nt=8)
#define NTHREADS 256
#define XPK_BYTES (NN * 32 * 2)   // 131072 B: packed x in d_ws
#define NEG_HALF_LOG_2PI (-0.91893853320467274f)

typedef __attribute__((ext_vector_type(8))) short short8;   // 8 bf16 (4 VGPRs) MFMA A/B frag
typedef __attribute__((ext_vector_type(4))) float f32x4;    // MFMA C/D frag
typedef __attribute__((ext_vector_type(2))) float f32x2;    // packed-math pair

// fp32 -> bf16 round-to-nearest-even (bit pattern) -- used for w1 (error-dominant term)
__device__ __forceinline__ short f2bf(float f) {
    unsigned u = __float_as_uint(f);
    u += 0x7fffu + ((u >> 16) & 1u);
    return (short)(u >> 16);
}

// R19 = green R18 + x-prepack hoisted out of the grid (R18 post-mortem: the
// per-wave bfrag build [~800 VALU + 104 scalar global loads] is redone once
// per r -> 256x redundant across the grid). A ~2us prep kernel writes
// xpk[n] = [hi(13)|0(3)|lo(13)|0(3)] (truncation split, same math as R18)
// into d_ws; the main kernel's bfrag build becomes 8 aligned
// global_load_dwordx4 (addr = n*64 + lo*32 + hi8*16, branch-free).
// d_ws is rewritten fully every call (0xAA re-poison safe); host guards on
// ws_size and falls back to the R18 in-kernel build if scratch is too small
// (branch is call-count-independent -> graph-capture safe).
// Ledger: relu-split BANNED (R3/R4/R15); divergent partial short8 writes
// BANNED (R11/R12); 256 thr, lb(,3), branch-free builds, direct relu = green.

__global__ __launch_bounds__(NTHREADS)
void xprep_kernel(const float* __restrict__ x, short* __restrict__ xpk) {
    const int n = blockIdx.x * NTHREADS + threadIdx.x;   // grid covers 2048 rows
    const float* xp = x + (size_t)n * IND;
    short tmp[32];
#pragma unroll
    for (int i = 0; i < 13; ++i) {
        float v = xp[i];
        unsigned u = __float_as_uint(v);
        tmp[i] = (short)(u >> 16);                         // hi: truncate to bf16
        float res = v - __uint_as_float(u & 0xffff0000u);  // exact remainder
        tmp[16 + i] = (short)(__float_as_uint(res) >> 16); // lo: truncate remainder
    }
    tmp[13] = 0; tmp[14] = 0; tmp[15] = 0;
    tmp[29] = 0; tmp[30] = 0; tmp[31] = 0;
    short8* dst = (short8*)(xpk + (size_t)n * 32);
    dst[0] = *(short8*)&tmp[0];
    dst[1] = *(short8*)&tmp[8];
    dst[2] = *(short8*)&tmp[16];
    dst[3] = *(short8*)&tmp[24];
}

// ---- common body: staging + main loop + epilogue; BFRAG_FROM_WS selects the
//      bfrag source (prepacked d_ws vs in-kernel build fallback) ----
template <bool FROM_WS>
__global__ __launch_bounds__(NTHREADS, 3)
void ffrelu_mfma_kernel(const float* __restrict__ x,
                        const float* __restrict__ y,
                        const float* __restrict__ w,
                        const short* __restrict__ xpk,
                        float* __restrict__ out) {
    __shared__ short Als[HH * 16];   // 16384 B: w1 rows [w1(13)|0(3)]
    __shared__ float w2s[HH];        // 2048 B, fp32

    const int tid = threadIdx.x;
    const int r = blockIdx.x;       // fast dim: same-r blocks -> same XCD
    const int wave = tid >> 6;
    const int lane = tid & 63;
    const int m = lane & 15;        // MFMA row/col index within 16
    const int q = lane >> 4;        // quad 0..3

    const float* wr = w + (size_t)r * WDIM;

    // ---- stage w1 (bf16 RNE, 2 rows/thread, pads inline) + w2; ONE barrier ----
#pragma unroll
    for (int rr = 0; rr < 2; ++rr) {
        const int h = tid * 2 + rr;
        const float* p = wr + (size_t)h * IND;
        short tmp[16];
#pragma unroll
        for (int i = 0; i < 13; ++i) tmp[i] = f2bf(p[i]);
        tmp[13] = 0; tmp[14] = 0; tmp[15] = 0;
        *(short8*)&Als[h * 16]     = *(short8*)&tmp[0];
        *(short8*)&Als[h * 16 + 8] = *(short8*)&tmp[8];
    }
    w2s[tid]       = wr[W1DIM + tid];
    w2s[tid + 256] = wr[W1DIM + tid + 256];
    __syncthreads();

    const bool lo  = (q >= 2);     // q2/q3 lanes carry x_lo
    const bool hi8 = (q & 1);      // q1/q3 lanes carry slice [8..12]
    const f32x2 zero2 = {0.0f, 0.0f};
    const f32x4 czero = {0.0f, 0.0f, 0.0f, 0.0f};   // loop-invariant C operand

    // ---- 8 B-frags (128 n per wave) ----
    const int nb = blockIdx.y * NBLK + wave * 128;
    short8 bfrag[8];
    if (FROM_WS) {
        // one aligned 16B load per frag: row nb+nt*16+m, half by lo, slice by hi8
        const short* base = xpk + (size_t)(nb + m) * 32 + (lo ? 16 : 0) + (hi8 ? 8 : 0);
#pragma unroll
        for (int nt = 0; nt < 8; ++nt) {
            bfrag[nt] = *(const short8*)(base + nt * 16 * 32);
        }
    } else {
        // fallback: in-kernel truncation build (R18 verbatim)
#pragma unroll
        for (int nt = 0; nt < 8; ++nt) {
            const float* xp = x + (size_t)(nb + nt * 16 + m) * IND;
            short hs[13], ls[13];
#pragma unroll
            for (int i = 0; i < 13; ++i) {
                float v = xp[i];
                unsigned u = __float_as_uint(v);
                hs[i] = (short)(u >> 16);
                float res = v - __uint_as_float(u & 0xffff0000u);
                ls[i] = (short)(__float_as_uint(res) >> 16);
            }
            short s[13];
#pragma unroll
            for (int i = 0; i < 13; ++i) s[i] = lo ? ls[i] : hs[i];
            short8 b;
            b[0] = hi8 ? s[8]     : s[0];
            b[1] = hi8 ? s[9]     : s[1];
            b[2] = hi8 ? s[10]    : s[2];
            b[3] = hi8 ? s[11]    : s[3];
            b[4] = hi8 ? s[12]    : s[4];
            b[5] = hi8 ? (short)0 : s[5];
            b[6] = hi8 ? (short)0 : s[6];
            b[7] = hi8 ? (short)0 : s[7];
            bfrag[nt] = b;
        }
    }

    // packed accumulators: muv[nt][0] covers regs {0,1}, muv[nt][1] regs {2,3}
    f32x2 muv[8][2];
#pragma unroll
    for (int i = 0; i < 8; ++i) {
        muv[i][0] = zero2;
        muv[i][1] = zero2;
    }

    // ---- main loop: 32 h-tiles x 8 n-tiles; packed relu+dot ----
#pragma unroll 2
    for (int t = 0; t < 32; ++t) {
        const short8 a = *(const short8*)&Als[(t * 16 + m) * 16 + (q & 1) * 8];
        const f32x4 wv = *(const f32x4*)&w2s[t * 16 + q * 4];
        const f32x2 wv01 = {wv[0], wv[1]};
        const f32x2 wv23 = {wv[2], wv[3]};
#pragma unroll
        for (int nt = 0; nt < 8; ++nt) {
            f32x4 c = __builtin_amdgcn_mfma_f32_16x16x32_bf16(a, bfrag[nt], czero, 0, 0, 0);
            // C layout: col n = lane&15, row h = t*16 + q*4 + reg
            f32x2 c01 = {c[0], c[1]};
            f32x2 c23 = {c[2], c[3]};
            c01 = __builtin_elementwise_max(c01, zero2);
            c23 = __builtin_elementwise_max(c23, zero2);
            muv[nt][0] += c01 * wv01;    // v_pk_fma_f32
            muv[nt][1] += c23 * wv23;
        }
    }

    // ---- horizontal sum + quad butterfly ----
    float mu[8];
#pragma unroll
    for (int nt = 0; nt < 8; ++nt) {
        f32x2 p = muv[nt][0] + muv[nt][1];
        float v = p[0] + p[1];
        v += __shfl_xor(v, 16, 64);
        v += __shfl_xor(v, 32, 64);
        mu[nt] = v;
    }

    // lane stores n = nb + s*64 + lane (s=0,1) -> tiles nt = q and 4+q
    float mu0, mu1;
    if (q == 0)      { mu0 = mu[0]; mu1 = mu[4]; }
    else if (q == 1) { mu0 = mu[1]; mu1 = mu[5]; }
    else if (q == 2) { mu0 = mu[2]; mu1 = mu[6]; }
    else             { mu0 = mu[3]; mu1 = mu[7]; }

    {
        const int n0 = nb + lane;
        float resid = y[n0] - mu0;
        out[(size_t)r * NN + n0] = fmaf(-0.5f * resid, resid, NEG_HALF_LOG_2PI);
    }
    {
        const int n1 = nb + 64 + lane;
        float resid = y[n1] - mu1;
        out[(size_t)r * NN + n1] = fmaf(-0.5f * resid, resid, NEG_HALF_LOG_2PI);
    }
}

extern "C" void kernel_launch(void* const* d_in, const int* in_sizes, int n_in,
                              void* d_out, int out_size, void* d_ws, size_t ws_size,
                              hipStream_t stream) {
    const float* x = (const float*)d_in[0];   // [N, 13]
    const float* y = (const float*)d_in[1];   // [N, 1]
    const float* w = (const float*)d_in[2];   // [R, 7168]
    float* out = (float*)d_out;               // [R, N]
    short* xpk = (short*)d_ws;                // [N, 32] packed bf16 hi/lo

    dim3 grid(RR, NN / NBLK);   // (256, 4): r fast -> same-r blocks share an XCD
    dim3 block(NTHREADS);

    if (ws_size >= (size_t)XPK_BYTES) {
        xprep_kernel<<<NN / NTHREADS, NTHREADS, 0, stream>>>(x, xpk);
        ffrelu_mfma_kernel<true><<<grid, block, 0, stream>>>(x, y, w, xpk, out);
    } else {
        ffrelu_mfma_kernel<false><<<grid, block, 0, stream>>>(x, y, w, xpk, out);
    }
}

// Round 20
// 91.355 us; speedup vs baseline: 1.0242x; 1.0218x over previous
//
#include <hip/hip_runtime.h>

#define HH 512
#define IND 13
#define NN 2048
#define RR 256
#define WDIM 7168      // (13+1)*512
#define W1DIM 6656     // 13*512
#define NBLK 256       // n per block (4 waves x 64 n, nt=4)
#define NTHREADS 256
#define XPK_BYTES (NN * 32 * 2)   // 131072 B: packed x in d_ws
#define NEG_HALF_LOG_2PI (-0.91893853320467274f)

typedef __attribute__((ext_vector_type(8))) short short8;   // 8 bf16 (4 VGPRs) MFMA A/B frag
typedef __attribute__((ext_vector_type(4))) float f32x4;    // MFMA C/D frag
typedef __attribute__((ext_vector_type(2))) float f32x2;    // packed-math pair

// fp32 -> bf16 round-to-nearest-even (bit pattern) -- used for w1 (error-dominant term)
__device__ __forceinline__ short f2bf(float f) {
    unsigned u = __float_as_uint(f);
    u += 0x7fffu + ((u >> 16) & 1u);
    return (short)(u >> 16);
}

// R20 = occupancy retest with build cost removed (R19 post-mortem: kernel is
// latency-bound, SIMDs ~90% idle-stalled at 4 blocks/CU; R18 occ 28%).
// Grid (256,8), NBLK=256, nt=4: 2048 blocks = exactly 8 blocks/CU (LDS 18432
// allows 8) -> up to 32 waves/CU, 2x R18's ceiling. Staging redone 8x/r but
// now cheap (~80 VALU/thread + L2-local w reads via XCD swizzle); bfrag =
// 4 aligned global_load_dwordx4 from the xpk prepack (R19).
// Ledger: relu-split BANNED (R3/R4/R15); divergent partial short8 writes
// BANNED (R11/R12); 512-thread blocks avoided (R5 confound); 256 thr, lb(,3),
// branch-free builds, direct relu = proven-green.

__global__ __launch_bounds__(NTHREADS)
void xprep_kernel(const float* __restrict__ x, short* __restrict__ xpk) {
    const int n = blockIdx.x * NTHREADS + threadIdx.x;   // grid covers 2048 rows
    const float* xp = x + (size_t)n * IND;
    short tmp[32];
#pragma unroll
    for (int i = 0; i < 13; ++i) {
        float v = xp[i];
        unsigned u = __float_as_uint(v);
        tmp[i] = (short)(u >> 16);                         // hi: truncate to bf16
        float res = v - __uint_as_float(u & 0xffff0000u);  // exact remainder
        tmp[16 + i] = (short)(__float_as_uint(res) >> 16); // lo: truncate remainder
    }
    tmp[13] = 0; tmp[14] = 0; tmp[15] = 0;
    tmp[29] = 0; tmp[30] = 0; tmp[31] = 0;
    short8* dst = (short8*)(xpk + (size_t)n * 32);
    dst[0] = *(short8*)&tmp[0];
    dst[1] = *(short8*)&tmp[8];
    dst[2] = *(short8*)&tmp[16];
    dst[3] = *(short8*)&tmp[24];
}

template <bool FROM_WS>
__global__ __launch_bounds__(NTHREADS, 3)
void ffrelu_mfma_kernel(const float* __restrict__ x,
                        const float* __restrict__ y,
                        const float* __restrict__ w,
                        const short* __restrict__ xpk,
                        float* __restrict__ out) {
    __shared__ short Als[HH * 16];   // 16384 B: w1 rows [w1(13)|0(3)]
    __shared__ float w2s[HH];        // 2048 B, fp32

    const int tid = threadIdx.x;
    const int r = blockIdx.x;       // fast dim: same-r blocks -> same XCD
    const int wave = tid >> 6;
    const int lane = tid & 63;
    const int m = lane & 15;        // MFMA row/col index within 16
    const int q = lane >> 4;        // quad 0..3

    const float* wr = w + (size_t)r * WDIM;

    // ---- stage w1 (bf16 RNE, 2 rows/thread, pads inline) + w2; ONE barrier ----
#pragma unroll
    for (int rr = 0; rr < 2; ++rr) {
        const int h = tid * 2 + rr;
        const float* p = wr + (size_t)h * IND;
        short tmp[16];
#pragma unroll
        for (int i = 0; i < 13; ++i) tmp[i] = f2bf(p[i]);
        tmp[13] = 0; tmp[14] = 0; tmp[15] = 0;
        *(short8*)&Als[h * 16]     = *(short8*)&tmp[0];
        *(short8*)&Als[h * 16 + 8] = *(short8*)&tmp[8];
    }
    w2s[tid]       = wr[W1DIM + tid];
    w2s[tid + 256] = wr[W1DIM + tid + 256];
    __syncthreads();

    const bool lo  = (q >= 2);     // q2/q3 lanes carry x_lo
    const bool hi8 = (q & 1);      // q1/q3 lanes carry slice [8..12]
    const f32x2 zero2 = {0.0f, 0.0f};
    const f32x4 czero = {0.0f, 0.0f, 0.0f, 0.0f};   // loop-invariant C operand

    // ---- 4 B-frags (64 n per wave) ----
    const int nb = blockIdx.y * NBLK + wave * 64;
    short8 bfrag[4];
    if (FROM_WS) {
        // one aligned 16B load per frag: row nb+nt*16+m, half by lo, slice by hi8
        const short* base = xpk + (size_t)(nb + m) * 32 + (lo ? 16 : 0) + (hi8 ? 8 : 0);
#pragma unroll
        for (int nt = 0; nt < 4; ++nt) {
            bfrag[nt] = *(const short8*)(base + nt * 16 * 32);
        }
    } else {
        // fallback: in-kernel truncation build (branch-free)
#pragma unroll
        for (int nt = 0; nt < 4; ++nt) {
            const float* xp = x + (size_t)(nb + nt * 16 + m) * IND;
            short hs[13], ls[13];
#pragma unroll
            for (int i = 0; i < 13; ++i) {
                float v = xp[i];
                unsigned u = __float_as_uint(v);
                hs[i] = (short)(u >> 16);
                float res = v - __uint_as_float(u & 0xffff0000u);
                ls[i] = (short)(__float_as_uint(res) >> 16);
            }
            short s[13];
#pragma unroll
            for (int i = 0; i < 13; ++i) s[i] = lo ? ls[i] : hs[i];
            short8 b;
            b[0] = hi8 ? s[8]     : s[0];
            b[1] = hi8 ? s[9]     : s[1];
            b[2] = hi8 ? s[10]    : s[2];
            b[3] = hi8 ? s[11]    : s[3];
            b[4] = hi8 ? s[12]    : s[4];
            b[5] = hi8 ? (short)0 : s[5];
            b[6] = hi8 ? (short)0 : s[6];
            b[7] = hi8 ? (short)0 : s[7];
            bfrag[nt] = b;
        }
    }

    // packed accumulators: muv[nt][0] covers regs {0,1}, muv[nt][1] regs {2,3}
    f32x2 muv[4][2];
#pragma unroll
    for (int i = 0; i < 4; ++i) {
        muv[i][0] = zero2;
        muv[i][1] = zero2;
    }

    // ---- main loop: 32 h-tiles x 4 n-tiles; packed relu+dot ----
#pragma unroll 2
    for (int t = 0; t < 32; ++t) {
        const short8 a = *(const short8*)&Als[(t * 16 + m) * 16 + (q & 1) * 8];
        const f32x4 wv = *(const f32x4*)&w2s[t * 16 + q * 4];
        const f32x2 wv01 = {wv[0], wv[1]};
        const f32x2 wv23 = {wv[2], wv[3]};
#pragma unroll
        for (int nt = 0; nt < 4; ++nt) {
            f32x4 c = __builtin_amdgcn_mfma_f32_16x16x32_bf16(a, bfrag[nt], czero, 0, 0, 0);
            // C layout: col n = lane&15, row h = t*16 + q*4 + reg
            f32x2 c01 = {c[0], c[1]};
            f32x2 c23 = {c[2], c[3]};
            c01 = __builtin_elementwise_max(c01, zero2);
            c23 = __builtin_elementwise_max(c23, zero2);
            muv[nt][0] += c01 * wv01;    // v_pk_fma_f32
            muv[nt][1] += c23 * wv23;
        }
    }

    // ---- horizontal sum + quad butterfly ----
    float mu[4];
#pragma unroll
    for (int nt = 0; nt < 4; ++nt) {
        f32x2 p = muv[nt][0] + muv[nt][1];
        float v = p[0] + p[1];
        v += __shfl_xor(v, 16, 64);
        v += __shfl_xor(v, 32, 64);
        mu[nt] = v;
    }

    // lane stores n = nb + lane = nb + q*16 + m -> tile nt=q, col m
    float mu0;
    if (q == 0)      mu0 = mu[0];
    else if (q == 1) mu0 = mu[1];
    else if (q == 2) mu0 = mu[2];
    else             mu0 = mu[3];

    const int n0 = nb + lane;
    float resid0 = y[n0] - mu0;
    out[(size_t)r * NN + n0] = fmaf(-0.5f * resid0, resid0, NEG_HALF_LOG_2PI);
}

extern "C" void kernel_launch(void* const* d_in, const int* in_sizes, int n_in,
                              void* d_out, int out_size, void* d_ws, size_t ws_size,
                              hipStream_t stream) {
    const float* x = (const float*)d_in[0];   // [N, 13]
    const float* y = (const float*)d_in[1];   // [N, 1]
    const float* w = (const float*)d_in[2];   // [R, 7168]
    float* out = (float*)d_out;               // [R, N]
    short* xpk = (short*)d_ws;                // [N, 32] packed bf16 hi/lo

    dim3 grid(RR, NN / NBLK);   // (256, 8): r fast -> same-r blocks share an XCD
    dim3 block(NTHREADS);

    if (ws_size >= (size_t)XPK_BYTES) {
        xprep_kernel<<<NN / NTHREADS, NTHREADS, 0, stream>>>(x, xpk);
        ffrelu_mfma_kernel<true><<<grid, block, 0, stream>>>(x, y, w, xpk, out);
    } else {
        ffrelu_mfma_kernel<false><<<grid, block, 0, stream>>>(x, y, w, xpk, out);
    }
}